// Round 1
// 197.840 us; speedup vs baseline: 1.2647x; 1.2647x over previous
//
#include <hip/hip_runtime.h>
#include <math.h>

#define B_ROWS   1024
#define DIM      192
#define NCLS     100000
#define S_SCALE  30.0f
#define COS_M    0.98006657784124163f
#define SIN_M    0.19866933079506122f
#define TH_C     (-0.98006657784124163f)
#define MM_C     0.039733866159012243f
#define L2E30    43.2808512266689f      // 30 * log2(e)

// ---- old-path constants (kept as fallback when workspace is small) ----
#define NTILE_B  784      // 128-class tiles (784*128 = 100352)
#define NCHUNKR  16       // 64-row chunks of A
#define ASEG_CH  1536     // segs per A chunk: 24 k8-groups * 64 rows
#define NSLOT    1568     // old stats slots: tile * 2 csel halves

// ---- new-path constants: class-streaming orientation ----
#define NCHUNKC  1568     // 64-class chunks total (1568*64 = 100352)
#define CSPLIT   64       // class splits (pslot slots per row)
#define NSLOT2   64
#define PACK_WGRID 3136   // 100352/32 rows per block
#define PACK_GRID  3168   // + 1024/32 x blocks

typedef float floatx4 __attribute__((ext_vector_type(4)));
typedef __bf16 bf16x8 __attribute__((ext_vector_type(8)));

__device__ __forceinline__ unsigned int f2bf(float x) {
    unsigned int u = __float_as_uint(x);
    u = (u + 0x7fffu + ((u >> 16) & 1u)) >> 16;   // RNE
    return u;
}
__device__ __forceinline__ unsigned int pack2(float lo, float hi) {
    return f2bf(lo) | (f2bf(hi) << 16);
}
// raw v_exp_f32 (args here are in [-87, 1] — safe range, no libm guards needed)
__device__ __forceinline__ float fexp2(float x) {
#if __has_builtin(__builtin_amdgcn_exp2f)
    return __builtin_amdgcn_exp2f(x);
#else
    float r; __asm__("v_exp_f32 %0, %1" : "=v"(r) : "v"(x)); return r;
#endif
}
// 16-lane rotate (DPP row_ror:N) — reduce over the C-layout col lanes
template <int N>
__device__ __forceinline__ float ror16(float x) {
    return __int_as_float(__builtin_amdgcn_mov_dpp(
        __float_as_int(x), 0x120 | N, 0xF, 0xF, false));
}

// ===========================================================================
// NEW PATH
// ===========================================================================

// ---------------------------------------------------------------------------
// pack_kernel: fused normalize + bf16 pack + MFMA-order swizzle for BOTH
// w (blocks 0..3135 -> wsw) and x (blocks 3136..3167 -> asw). 8 threads/row,
// 32 rows/block. Layout (shared with asw): dst[((cc*24 + k8)*64 + c64)*8].
// Block 3136 also zeroes the accumulator.
// ---------------------------------------------------------------------------
__global__ __launch_bounds__(256)
void pack_kernel(const float* __restrict__ x, const float* __restrict__ w,
                 unsigned short* __restrict__ asw, unsigned short* __restrict__ wsw,
                 float* __restrict__ accum)
{
    const int bid = blockIdx.x;
    const int t = threadIdx.x;
    const int r = t >> 3, oct = t & 7;

    const float* src;
    unsigned short* dst;
    int row;
    bool live;
    if (bid < PACK_WGRID) {
        row = bid * 32 + r;  live = (row < NCLS);  src = w;  dst = wsw;
    } else {
        row = (bid - PACK_WGRID) * 32 + r;  live = true;  src = x;  dst = asw;
        if (bid == PACK_WGRID && t < 4) accum[t] = 0.0f;
    }

    float4 buf[6];
    float s = 0.f;
    if (live) {
        const float4* sp = (const float4*)(src + (size_t)row * DIM) + oct * 6;
        #pragma unroll
        for (int q = 0; q < 6; ++q) {
            float4 v = sp[q];
            buf[q] = v;
            s += v.x * v.x + v.y * v.y + v.z * v.z + v.w * v.w;
        }
    } else {
        #pragma unroll
        for (int q = 0; q < 6; ++q) buf[q] = make_float4(0.f, 0.f, 0.f, 0.f);
    }
    s += __shfl_xor(s, 1);
    s += __shfl_xor(s, 2);
    s += __shfl_xor(s, 4);
    const float inv = live ? (1.0f / fmaxf(sqrtf(s), 1e-12f)) : 0.0f;

    const int cc = row >> 6, c64 = row & 63;
    #pragma unroll
    for (int j = 0; j < 3; ++j) {
        const int k8 = oct * 3 + j;
        uint4 o;
        float4 a0 = buf[2 * j], a1 = buf[2 * j + 1];
        o.x = pack2(a0.x * inv, a0.y * inv);
        o.y = pack2(a0.z * inv, a0.w * inv);
        o.z = pack2(a1.x * inv, a1.y * inv);
        o.w = pack2(a1.z * inv, a1.w * inv);
        *(uint4*)(dst + ((size_t)(cc * 24 + k8) * 64 + c64) * 8) = o;
    }
}

// ---------------------------------------------------------------------------
// gemm_stats2: class-STREAMING orientation (flash-attention style).
// Block = (row-tile rt of 64 x-rows) x (class-split cs of ~1568 classes).
// Wave owns 16 x-rows: A-frags live in 24 VGPRs for the whole kernel.
// Streams 64-class chunks of pre-packed wsw; softmax stats (fixed-base-30
// m, s) ACCUMULATE IN REGISTERS across the stream — the 16-lane DPP reduce
// happens ONCE at the end, and each wave writes 16 fp32 (m,s) pairs total.
// No LDS, no barriers. Grid 1024 = exactly 4 blocks/CU resident.
// XCD-bijective swizzle: each XCD owns a contiguous 8-cs class range so the
// 16 row-tile blocks sharing it hit the same L2.
// ---------------------------------------------------------------------------
__global__ __launch_bounds__(256, 4)
void gemm_stats2_kernel(const unsigned short* __restrict__ asw,
                        const unsigned short* __restrict__ wsw,
                        float2* __restrict__ pslot)
{
    const int bid  = blockIdx.x;
    const int cs   = (bid & 7) * 8 + ((bid >> 3) & 7);   // class split 0..63
    const int rt   = bid >> 6;                           // row tile 0..15
    const int tid  = threadIdx.x;
    const int wv   = tid >> 6;
    const int lane = tid & 63;
    const int quad = lane >> 4, mrow = lane & 15;

    // persistent A fragments: 16 x-rows * 192 k = 24 VGPRs
    bf16x8 xfr[6];
    {
        const unsigned short* ab = asw + (size_t)rt * (ASEG_CH * 8);
        #pragma unroll
        for (int ks = 0; ks < 6; ++ks)
            xfr[ks] = *(const bf16x8*)(ab +
                (size_t)((ks * 4 + quad) * 64 + wv * 16 + mrow) * 8);
    }

    // chunk range: even cs take 25 chunks, odd take 24 (32*25+32*24 = 1568)
    const int nch = 24 + ((cs & 1) ? 0 : 1);
    const unsigned short* wp = wsw
        + (size_t)(cs * 24 + ((cs + 1) >> 1)) * 12288   // chunk base (shorts)
        + quad * 512 + mrow * 8;                        // per-lane offset

    float s_acc[4] = {0.f, 0.f, 0.f, 0.f};
    float m_acc[4] = {-1e30f, -1e30f, -1e30f, -1e30f};

    // prefetch first ks of first chunk
    bf16x8 c0 = *(const bf16x8*)(wp);
    bf16x8 c1 = *(const bf16x8*)(wp + 128);
    bf16x8 c2 = *(const bf16x8*)(wp + 256);
    bf16x8 c3 = *(const bf16x8*)(wp + 384);

    #pragma unroll 1
    for (int c = 0; c < nch; ++c, wp += 12288) {
        floatx4 acc0 = {0.f, 0.f, 0.f, 0.f};
        floatx4 acc1 = {0.f, 0.f, 0.f, 0.f};
        floatx4 acc2 = {0.f, 0.f, 0.f, 0.f};
        floatx4 acc3 = {0.f, 0.f, 0.f, 0.f};
        #pragma unroll
        for (int ks = 0; ks < 6; ++ks) {
            // prefetch next ks (or next chunk's ks0; trailing overread of the
            // final chunk lands in the pslot region — allocated, unused)
            const unsigned short* np = (ks < 5) ? (wp + (ks + 1) * 2048)
                                                : (wp + 12288);
            bf16x8 n0 = *(const bf16x8*)(np);
            bf16x8 n1 = *(const bf16x8*)(np + 128);
            bf16x8 n2 = *(const bf16x8*)(np + 256);
            bf16x8 n3 = *(const bf16x8*)(np + 384);
            acc0 = __builtin_amdgcn_mfma_f32_16x16x32_bf16(xfr[ks], c0, acc0, 0, 0, 0);
            acc1 = __builtin_amdgcn_mfma_f32_16x16x32_bf16(xfr[ks], c1, acc1, 0, 0, 0);
            acc2 = __builtin_amdgcn_mfma_f32_16x16x32_bf16(xfr[ks], c2, acc2, 0, 0, 0);
            acc3 = __builtin_amdgcn_mfma_f32_16x16x32_bf16(xfr[ks], c3, acc3, 0, 0, 0);
            c0 = n0; c1 = n1; c2 = n2; c3 = n3;
        }
        // in-register stats accumulation: ~3.5 VALU/output, zero cross-lane
        #pragma unroll
        for (int r = 0; r < 4; ++r) {
            float v0 = acc0[r], v1 = acc1[r], v2 = acc2[r], v3 = acc3[r];
            m_acc[r] = fmaxf(m_acc[r], fmaxf(fmaxf(v0, v1), fmaxf(v2, v3)));
            s_acc[r] += (fexp2(fmaf(v0, L2E30, -L2E30))
                       + fexp2(fmaf(v1, L2E30, -L2E30)))
                      + (fexp2(fmaf(v2, L2E30, -L2E30))
                       + fexp2(fmaf(v3, L2E30, -L2E30)));
        }
    }

    // ONE cross-lane reduce per kernel (over the 16 class-lanes) + fp32 write
    const int rowb = rt * 64 + wv * 16 + quad * 4;
    #pragma unroll
    for (int r = 0; r < 4; ++r) {
        float s = s_acc[r], m = m_acc[r];
        s += ror16<1>(s); s += ror16<2>(s); s += ror16<4>(s); s += ror16<8>(s);
        m = fmaxf(m, ror16<1>(m)); m = fmaxf(m, ror16<2>(m));
        m = fmaxf(m, ror16<4>(m)); m = fmaxf(m, ror16<8>(m));
        if (mrow == 0)
            pslot[(size_t)cs * B_ROWS + rowb + r] = make_float2(m, s);
    }
}

// ---------------------------------------------------------------------------
// finalize2: merge 64 fp32 slots/row, ArcFace margin correction, loss+prec1.
// ---------------------------------------------------------------------------
__global__ __launch_bounds__(256)
void finalize2_kernel(const float2* __restrict__ pslot,
                      const float* __restrict__ x, const float* __restrict__ w,
                      const int* __restrict__ label,
                      float* __restrict__ accum, float* __restrict__ out)
{
    __shared__ float2 red[8][32];
    const int t = threadIdx.x, rr = t & 31, g = t >> 5;
    {
        const int row = blockIdx.x * 32 + rr;
        float M = -1e30f, L = 0.f;
        #pragma unroll
        for (int s = 0; s < NSLOT2 / 8; ++s) {
            float2 p = pslot[(size_t)(s * 8 + g) * B_ROWS + row];
            M = fmaxf(M, p.x);
            L += p.y;
        }
        red[g][rr] = make_float2(M, L);
    }
    __syncthreads();
    if (t < 32) {
        const int row = blockIdx.x * 32 + t;
        float Mc = -1e30f, L = 0.f;
        #pragma unroll
        for (int g2 = 0; g2 < 8; ++g2) {
            float2 p = red[g2][t];
            Mc = fmaxf(Mc, p.x);
            L += p.y;
        }

        const int lab = label[row];
        const float4* xr = (const float4*)(x + (size_t)row * DIM);
        const float4* wr = (const float4*)(w + (size_t)lab * DIM);
        float dot = 0.f, nx = 0.f, nw = 0.f;
        #pragma unroll
        for (int q = 0; q < 48; ++q) {
            float4 a = xr[q], b = wr[q];
            dot += a.x * b.x + a.y * b.y + a.z * b.z + a.w * b.w;
            nx  += a.x * a.x + a.y * a.y + a.z * a.z + a.w * a.w;
            nw  += b.x * b.x + b.y * b.y + b.z * b.z + b.w * b.w;
        }
        float cosl    = dot / fmaxf(sqrtf(nx) * sqrtf(nw), 1e-12f);
        float t_plain = S_SCALE * cosl;
        float sine    = sqrtf(fmaxf(0.f, fminf(1.f, 1.f - cosl * cosl)));
        float phi     = cosl * COS_M - sine * SIN_M;
        float modv    = ((cosl - TH_C) > 0.f) ? phi : (cosl - MM_C);
        float t_mod   = S_SCALE * modv;

        float Ladj = L - __expf(t_plain - 30.0f) + __expf(t_mod - 30.0f);
        Ladj = fmaxf(Ladj, 1e-37f);
        float loss = (30.0f + logf(Ladj)) - t_mod;
        float corr = (t_mod > S_SCALE * Mc) ? 1.f : 0.f;

        #pragma unroll
        for (int off = 16; off > 0; off >>= 1) {
            loss += __shfl_xor(loss, off);
            corr += __shfl_xor(corr, off);
        }
        if (t == 0) {
            atomicAdd(&accum[0], loss);
            atomicAdd(&accum[1], corr);
            __threadfence();
            int old = atomicAdd((int*)accum + 2, 1);
            if (old == (int)gridDim.x - 1) {
                float a0 = atomicAdd(&accum[0], 0.0f);
                float a1 = atomicAdd(&accum[1], 0.0f);
                out[0] = a0 * (1.0f / (float)B_ROWS);
                out[1] = a1 * (100.0f / (float)B_ROWS);
            }
        }
    }
}

// ===========================================================================
// OLD PATH (verified fallback, used only if workspace is too small)
// ===========================================================================

__global__ __launch_bounds__(256)
void prep_kernel(const float* __restrict__ x, unsigned short* __restrict__ asw,
                 float* __restrict__ accum)
{
    const int ab = blockIdx.x;            // 0..7
    const int t = threadIdx.x;
    if (ab == 0 && t < 4) accum[t] = 0.0f;
    const int r = t >> 1, half = t & 1;
    const int row = ab * 128 + r;
    const int c = ab * 2 + (r >> 6);      // A chunk index (64-row chunks)
    const int r64 = r & 63;

    float4 buf[24];
    float s = 0.f;
    const float4* sp = (const float4*)(x + (size_t)row * DIM) + half * 24;
    #pragma unroll
    for (int q = 0; q < 24; ++q) {
        float4 v = sp[q];
        buf[q] = v;
        s += v.x * v.x + v.y * v.y + v.z * v.z + v.w * v.w;
    }
    s += __shfl_xor(s, 1);
    const float inv = 1.0f / fmaxf(sqrtf(s), 1e-12f);
    #pragma unroll
    for (int j = 0; j < 12; ++j) {
        const int k8 = half * 12 + j;
        uint4 o;
        float4 a0 = buf[2 * j], a1 = buf[2 * j + 1];
        o.x = pack2(a0.x * inv, a0.y * inv);
        o.y = pack2(a0.z * inv, a0.w * inv);
        o.z = pack2(a1.x * inv, a1.y * inv);
        o.w = pack2(a1.z * inv, a1.w * inv);
        *(uint4*)(asw + ((size_t)c * ASEG_CH + k8 * 64 + r64) * 8) = o;
    }
}

__global__ __launch_bounds__(256, 3)
void gemm_stats_kernel(const float* __restrict__ w,
                       const unsigned short* __restrict__ asw,
                       unsigned int* __restrict__ pslot)
{
    __shared__ __align__(16) char lds[49152];
    const int tid  = threadIdx.x;
    const int wave = tid >> 6;
    const int lane = tid & 63;
    const int quad = lane >> 4;
    const int mrow = lane & 15;
    const int rg   = wave >> 1;
    const int cgr  = wave & 1;

    {
        const int r = tid >> 1, half = tid & 1;
        const int col = blockIdx.x * 128 + r;
        const bool live = (col < NCLS);
        float4 buf[24];
        float s = 0.f;
        if (live) {
            const float4* sp = (const float4*)(w + (size_t)col * DIM) + half * 24;
            #pragma unroll
            for (int q = 0; q < 24; ++q) {
                float4 v = sp[q];
                buf[q] = v;
                s += v.x * v.x + v.y * v.y + v.z * v.z + v.w * v.w;
            }
        }
        s += __shfl_xor(s, 1);
        const float inv = live ? (1.0f / fmaxf(sqrtf(s), 1e-12f)) : 0.0f;
        #pragma unroll
        for (int j = 0; j < 12; ++j) {
            const int k8 = half * 12 + j;
            uint4 o = make_uint4(0u, 0u, 0u, 0u);
            if (live) {
                float4 a0 = buf[2 * j], a1 = buf[2 * j + 1];
                o.x = pack2(a0.x * inv, a0.y * inv);
                o.y = pack2(a0.z * inv, a0.w * inv);
                o.z = pack2(a1.x * inv, a1.y * inv);
                o.w = pack2(a1.z * inv, a1.w * inv);
            }
            *(uint4*)(lds + (size_t)(k8 * 128 + r) * 16) = o;
        }
    }
    __syncthreads();

    bf16x8 bfr[6][4];
    #pragma unroll
    for (int ks = 0; ks < 6; ++ks)
        #pragma unroll
        for (int ni = 0; ni < 4; ++ni)
            bfr[ks][ni] = *(const bf16x8*)(lds +
                (((ks * 4 + quad) * 128) + cgr * 64 + ni * 16 + mrow) * 16);

    const int slot = blockIdx.x * 2 + cgr;
    #pragma unroll 2
    for (int c = 0; c < NCHUNKR; ++c) {
        const unsigned short* ab = asw + (size_t)c * ASEG_CH * 8;
        floatx4 acc[2][4];
        #pragma unroll
        for (int mi = 0; mi < 2; ++mi)
            #pragma unroll
            for (int ni = 0; ni < 4; ++ni) {
                floatx4 z = {0.f, 0.f, 0.f, 0.f};
                acc[mi][ni] = z;
            }
        #pragma unroll
        for (int ks = 0; ks < 6; ++ks) {
            bf16x8 a0 = *(const bf16x8*)(ab +
                (size_t)(((ks * 4 + quad) * 64) + rg * 32 + mrow) * 8);
            bf16x8 a1 = *(const bf16x8*)(ab +
                (size_t)(((ks * 4 + quad) * 64) + rg * 32 + 16 + mrow) * 8);
            #pragma unroll
            for (int ni = 0; ni < 4; ++ni)
                acc[0][ni] = __builtin_amdgcn_mfma_f32_16x16x32_bf16(
                    a0, bfr[ks][ni], acc[0][ni], 0, 0, 0);
            #pragma unroll
            for (int ni = 0; ni < 4; ++ni)
                acc[1][ni] = __builtin_amdgcn_mfma_f32_16x16x32_bf16(
                    a1, bfr[ks][ni], acc[1][ni], 0, 0, 0);
        }

        #pragma unroll
        for (int mi = 0; mi < 2; ++mi)
            #pragma unroll
            for (int r = 0; r < 4; ++r) {
                float v0 = acc[mi][0][r], v1 = acc[mi][1][r];
                float v2 = acc[mi][2][r], v3 = acc[mi][3][r];
                float m = fmaxf(fmaxf(v0, v1), fmaxf(v2, v3));
                float s = fexp2(fmaf(v0, L2E30, -L2E30))
                        + fexp2(fmaf(v1, L2E30, -L2E30))
                        + fexp2(fmaf(v2, L2E30, -L2E30))
                        + fexp2(fmaf(v3, L2E30, -L2E30));
                s += ror16<1>(s); s += ror16<2>(s);
                s += ror16<4>(s); s += ror16<8>(s);
                m = fmaxf(m, ror16<1>(m)); m = fmaxf(m, ror16<2>(m));
                m = fmaxf(m, ror16<4>(m)); m = fmaxf(m, ror16<8>(m));
                if (mrow == mi * 4 + r)
                    pslot[(size_t)slot * B_ROWS +
                          c * 64 + rg * 32 + mi * 16 + quad * 4 + r] = pack2(m, s);
            }
    }
}

__global__ __launch_bounds__(256)
void finalize_kernel(const unsigned int* __restrict__ pslot,
                     const float* __restrict__ x, const float* __restrict__ w,
                     const int* __restrict__ label,
                     float* __restrict__ accum, float* __restrict__ out)
{
    __shared__ float2 red[8][32];
    const int t = threadIdx.x, rr = t & 31, g = t >> 5;
    {
        const int row = blockIdx.x * 32 + rr;
        float M = -1e30f, L = 0.f;
        for (int s = g; s < NSLOT; s += 8) {
            unsigned int u = pslot[(size_t)s * B_ROWS + row];
            M = fmaxf(M, __uint_as_float(u << 16));
            L += __uint_as_float(u & 0xFFFF0000u);
        }
        red[g][rr] = make_float2(M, L);
    }
    __syncthreads();
    if (t < 32) {
        const int row = blockIdx.x * 32 + t;
        float Mc = -1e30f, L = 0.f;
        #pragma unroll
        for (int g2 = 0; g2 < 8; ++g2) {
            float2 p = red[g2][t];
            Mc = fmaxf(Mc, p.x);
            L += p.y;
        }

        const int lab = label[row];
        const float4* xr = (const float4*)(x + (size_t)row * DIM);
        const float4* wr = (const float4*)(w + (size_t)lab * DIM);
        float dot = 0.f, nx = 0.f, nw = 0.f;
        #pragma unroll
        for (int q = 0; q < 48; ++q) {
            float4 a = xr[q], b = wr[q];
            dot += a.x * b.x + a.y * b.y + a.z * b.z + a.w * b.w;
            nx  += a.x * a.x + a.y * a.y + a.z * a.z + a.w * a.w;
            nw  += b.x * b.x + b.y * b.y + b.z * b.z + b.w * b.w;
        }
        float cosl    = dot / fmaxf(sqrtf(nx) * sqrtf(nw), 1e-12f);
        float t_plain = S_SCALE * cosl;
        float sine    = sqrtf(fmaxf(0.f, fminf(1.f, 1.f - cosl * cosl)));
        float phi     = cosl * COS_M - sine * SIN_M;
        float modv    = ((cosl - TH_C) > 0.f) ? phi : (cosl - MM_C);
        float t_mod   = S_SCALE * modv;

        float Ladj = L - __expf(t_plain - 30.0f) + __expf(t_mod - 30.0f);
        Ladj = fmaxf(Ladj, 1e-37f);
        float loss = (30.0f + logf(Ladj)) - t_mod;
        float corr = (t_mod > S_SCALE * Mc) ? 1.f : 0.f;

        #pragma unroll
        for (int off = 16; off > 0; off >>= 1) {
            loss += __shfl_xor(loss, off);
            corr += __shfl_xor(corr, off);
        }
        if (t == 0) {
            atomicAdd(&accum[0], loss);
            atomicAdd(&accum[1], corr);
            __threadfence();
            int old = atomicAdd((int*)accum + 2, 1);
            if (old == (int)gridDim.x - 1) {
                float a0 = atomicAdd(&accum[0], 0.0f);
                float a1 = atomicAdd(&accum[1], 0.0f);
                out[0] = a0 * (1.0f / (float)B_ROWS);
                out[1] = a1 * (100.0f / (float)B_ROWS);
            }
        }
    }
}

// ---------------------------------------------------------------------------
extern "C" void kernel_launch(void* const* d_in, const int* in_sizes, int n_in,
                              void* d_out, int out_size, void* d_ws, size_t ws_size,
                              hipStream_t stream)
{
    const float* x     = (const float*)d_in[0];
    const float* w     = (const float*)d_in[1];
    const int*   label = (const int*)d_in[2];
    float* out = (float*)d_out;

    char* ws = (char*)d_ws;
    float* accum = (float*)ws;
    unsigned short* asw = (unsigned short*)(ws + 256);
    const size_t asw_bytes = (size_t)NCHUNKR * ASEG_CH * 16;           // 393216

    const size_t wsw_bytes   = (size_t)NCHUNKC * 24 * 64 * 16;        // 38535168
    const size_t pslot2_bytes = (size_t)NSLOT2 * B_ROWS * 8;          // 524288
    const size_t need_new = 256 + asw_bytes + wsw_bytes + pslot2_bytes;

    if (ws_size >= need_new) {
        unsigned short* wsw = (unsigned short*)(ws + 256 + asw_bytes);
        float2* pslot2 = (float2*)(ws + 256 + asw_bytes + wsw_bytes);
        pack_kernel<<<dim3(PACK_GRID), dim3(256), 0, stream>>>(x, w, asw, wsw, accum);
        gemm_stats2_kernel<<<dim3(1024), dim3(256), 0, stream>>>(asw, wsw, pslot2);
        finalize2_kernel<<<dim3(B_ROWS / 32), dim3(256), 0, stream>>>(
            pslot2, x, w, label, accum, out);
    } else {
        unsigned int* pslot = (unsigned int*)(ws + 256 + asw_bytes);
        prep_kernel<<<dim3(8), dim3(256), 0, stream>>>(x, asw, accum);
        gemm_stats_kernel<<<dim3(NTILE_B), dim3(256), 0, stream>>>(w, asw, pslot);
        finalize_kernel<<<dim3(B_ROWS / 32), dim3(256), 0, stream>>>(
            pslot, x, w, label, accum, out);
    }
}

// Round 2
// 162.504 us; speedup vs baseline: 1.5397x; 1.2174x over previous
//
#include <hip/hip_runtime.h>
#include <math.h>

#define B_ROWS   1024
#define DIM      192
#define NCLS     100000
#define S_SCALE  30.0f
#define COS_M    0.98006657784124163f
#define SIN_M    0.19866933079506122f
#define TH_C     (-0.98006657784124163f)
#define MM_C     0.039733866159012243f
#define L2E30    43.2808512266689f      // 30 * log2(e)

// ---- old-path constants (kept as fallback when workspace is small) ----
#define NTILE_B  784      // 128-class tiles (784*128 = 100352)
#define NCHUNKR  16       // 64-row chunks of A
#define ASEG_CH  1536     // segs per A chunk: 24 k8-groups * 64 rows
#define NSLOT    1568     // old stats slots: tile * 2 csel halves

// ---- new-path constants: class-streaming orientation ----
#define NCHUNKC  1568     // 64-class chunks total (1568*64 = 100352)
#define CSPLIT   128      // class splits (pslot slots per row)
#define NSLOT2   128
#define PACK_WGRID 3136   // 100352/32 rows per block
#define PACK_GRID  3168   // + 1024/32 x blocks

typedef float floatx4 __attribute__((ext_vector_type(4)));
typedef __bf16 bf16x8 __attribute__((ext_vector_type(8)));

__device__ __forceinline__ unsigned int f2bf(float x) {
    unsigned int u = __float_as_uint(x);
    u = (u + 0x7fffu + ((u >> 16) & 1u)) >> 16;   // RNE
    return u;
}
__device__ __forceinline__ unsigned int pack2(float lo, float hi) {
    return f2bf(lo) | (f2bf(hi) << 16);
}
// raw v_exp_f32 (args here are in [-87, 1] — safe range, no libm guards needed)
__device__ __forceinline__ float fexp2(float x) {
#if __has_builtin(__builtin_amdgcn_exp2f)
    return __builtin_amdgcn_exp2f(x);
#else
    float r; __asm__("v_exp_f32 %0, %1" : "=v"(r) : "v"(x)); return r;
#endif
}
// 16-lane rotate (DPP row_ror:N) — reduce over the C-layout col lanes
template <int N>
__device__ __forceinline__ float ror16(float x) {
    return __int_as_float(__builtin_amdgcn_mov_dpp(
        __float_as_int(x), 0x120 | N, 0xF, 0xF, false));
}

// ===========================================================================
// NEW PATH
// ===========================================================================

// ---------------------------------------------------------------------------
// pack_kernel: fused normalize + bf16 pack + MFMA-order swizzle for BOTH
// w (blocks 0..3135 -> wsw) and x (blocks 3136..3167 -> asw). 8 threads/row,
// 32 rows/block. Layout (shared with asw): dst[((cc*24 + k8)*64 + c64)*8].
// Block 3136 also zeroes the accumulator.
// ---------------------------------------------------------------------------
__global__ __launch_bounds__(256)
void pack_kernel(const float* __restrict__ x, const float* __restrict__ w,
                 unsigned short* __restrict__ asw, unsigned short* __restrict__ wsw,
                 float* __restrict__ accum)
{
    const int bid = blockIdx.x;
    const int t = threadIdx.x;
    const int r = t >> 3, oct = t & 7;

    const float* src;
    unsigned short* dst;
    int row;
    bool live;
    if (bid < PACK_WGRID) {
        row = bid * 32 + r;  live = (row < NCLS);  src = w;  dst = wsw;
    } else {
        row = (bid - PACK_WGRID) * 32 + r;  live = true;  src = x;  dst = asw;
        if (bid == PACK_WGRID && t < 4) accum[t] = 0.0f;
    }

    float4 buf[6];
    float s = 0.f;
    if (live) {
        const float4* sp = (const float4*)(src + (size_t)row * DIM) + oct * 6;
        #pragma unroll
        for (int q = 0; q < 6; ++q) {
            float4 v = sp[q];
            buf[q] = v;
            s += v.x * v.x + v.y * v.y + v.z * v.z + v.w * v.w;
        }
    } else {
        #pragma unroll
        for (int q = 0; q < 6; ++q) buf[q] = make_float4(0.f, 0.f, 0.f, 0.f);
    }
    s += __shfl_xor(s, 1);
    s += __shfl_xor(s, 2);
    s += __shfl_xor(s, 4);
    const float inv = live ? (1.0f / fmaxf(sqrtf(s), 1e-12f)) : 0.0f;

    const int cc = row >> 6, c64 = row & 63;
    #pragma unroll
    for (int j = 0; j < 3; ++j) {
        const int k8 = oct * 3 + j;
        uint4 o;
        float4 a0 = buf[2 * j], a1 = buf[2 * j + 1];
        o.x = pack2(a0.x * inv, a0.y * inv);
        o.y = pack2(a0.z * inv, a0.w * inv);
        o.z = pack2(a1.x * inv, a1.y * inv);
        o.w = pack2(a1.z * inv, a1.w * inv);
        *(uint4*)(dst + ((size_t)(cc * 24 + k8) * 64 + c64) * 8) = o;
    }
}

// ---------------------------------------------------------------------------
// gemm_stats3: class-streaming with M=64 rows PER WAVE (4 A-fragment sets,
// 96 VGPR). Each B-frag load now feeds 4 MFMAs -> per-CU load demand drops
// from ~211 B/cy (R1, L1-bound at ~19% MfmaUtil) to ~53 B/cy. Block = 4
// waves x 64 rows = 256 rows; grid = 4 row-blocks x 128 class-splits = 512
// = 2 blocks/CU at 2 waves/SIMD (VGPR ~240). Same-cs blocks are bid =
// cs, cs+128, cs+256, cs+384 == cs (mod 8) -> same XCD, shared L2 stream.
// Stats (fixed-base-30 m,s) accumulate in registers across the stream;
// ONE cross-lane reduce at the end. No LDS, no barriers.
// ---------------------------------------------------------------------------
__global__ __launch_bounds__(256, 2)
void gemm_stats3_kernel(const unsigned short* __restrict__ asw,
                        const unsigned short* __restrict__ wsw,
                        float2* __restrict__ pslot)
{
    const int bid  = blockIdx.x;
    const int cs   = bid & 127;          // class split 0..127
    const int rb   = bid >> 7;           // row block 0..3 (256 rows each)
    const int tid  = threadIdx.x;
    const int wv   = tid >> 6;
    const int lane = tid & 63;
    const int quad = lane >> 4, mrow = lane & 15;

    // persistent A fragments: 64 x-rows * 192 k = 96 VGPRs
    bf16x8 xfr[4][6];
    {
        const unsigned short* ab = asw + (size_t)(rb * 4 + wv) * (24 * 64 * 8);
        #pragma unroll
        for (int a = 0; a < 4; ++a)
            #pragma unroll
            for (int ks = 0; ks < 6; ++ks)
                xfr[a][ks] = *(const bf16x8*)(ab +
                    (size_t)((ks * 4 + quad) * 64 + a * 16 + mrow) * 8);
    }

    // chunk range: first 32 splits take 13 chunks, rest take 12 (= 1568)
    const int nch   = 12 + (cs < 32 ? 1 : 0);
    const int cbase = cs * 12 + (cs < 32 ? cs : 32);
    const unsigned short* wp = wsw + (size_t)cbase * 12288
                             + quad * 512 + mrow * 8;

    float s_acc[4][4];
    float m_acc[4][4];
    #pragma unroll
    for (int a = 0; a < 4; ++a)
        #pragma unroll
        for (int r = 0; r < 4; ++r) { s_acc[a][r] = 0.f; m_acc[a][r] = -1e30f; }

    // prefetch first ks of first chunk
    bf16x8 c0 = *(const bf16x8*)(wp);
    bf16x8 c1 = *(const bf16x8*)(wp + 128);
    bf16x8 c2 = *(const bf16x8*)(wp + 256);
    bf16x8 c3 = *(const bf16x8*)(wp + 384);

    #pragma unroll 1
    for (int c = 0; c < nch; ++c, wp += 12288) {
        floatx4 acc[4][4];
        #pragma unroll
        for (int a = 0; a < 4; ++a)
            #pragma unroll
            for (int ni = 0; ni < 4; ++ni) {
                floatx4 z = {0.f, 0.f, 0.f, 0.f};
                acc[a][ni] = z;
            }
        #pragma unroll
        for (int ks = 0; ks < 6; ++ks) {
            // prefetch next ks (or next chunk's ks0; trailing overread of the
            // final chunk lands in the pslot region — allocated, unused)
            const unsigned short* np = (ks < 5) ? (wp + (ks + 1) * 2048)
                                                : (wp + 12288);
            bf16x8 n0 = *(const bf16x8*)(np);
            bf16x8 n1 = *(const bf16x8*)(np + 128);
            bf16x8 n2 = *(const bf16x8*)(np + 256);
            bf16x8 n3 = *(const bf16x8*)(np + 384);
            #pragma unroll
            for (int a = 0; a < 4; ++a) {
                acc[a][0] = __builtin_amdgcn_mfma_f32_16x16x32_bf16(
                    xfr[a][ks], c0, acc[a][0], 0, 0, 0);
                acc[a][1] = __builtin_amdgcn_mfma_f32_16x16x32_bf16(
                    xfr[a][ks], c1, acc[a][1], 0, 0, 0);
                acc[a][2] = __builtin_amdgcn_mfma_f32_16x16x32_bf16(
                    xfr[a][ks], c2, acc[a][2], 0, 0, 0);
                acc[a][3] = __builtin_amdgcn_mfma_f32_16x16x32_bf16(
                    xfr[a][ks], c3, acc[a][3], 0, 0, 0);
            }
            c0 = n0; c1 = n1; c2 = n2; c3 = n3;
        }
        // in-register stats accumulation: zero cross-lane inside the stream
        #pragma unroll
        for (int a = 0; a < 4; ++a)
            #pragma unroll
            for (int r = 0; r < 4; ++r) {
                float v0 = acc[a][0][r], v1 = acc[a][1][r];
                float v2 = acc[a][2][r], v3 = acc[a][3][r];
                m_acc[a][r] = fmaxf(m_acc[a][r],
                                    fmaxf(fmaxf(v0, v1), fmaxf(v2, v3)));
                s_acc[a][r] += (fexp2(fmaf(v0, L2E30, -L2E30))
                              + fexp2(fmaf(v1, L2E30, -L2E30)))
                             + (fexp2(fmaf(v2, L2E30, -L2E30))
                              + fexp2(fmaf(v3, L2E30, -L2E30)));
            }
    }

    // ONE cross-lane reduce per kernel (over the 16 class-lanes) + fp32 write
    const int rowb = rb * 256 + wv * 64;
    #pragma unroll
    for (int a = 0; a < 4; ++a)
        #pragma unroll
        for (int r = 0; r < 4; ++r) {
            float s = s_acc[a][r], m = m_acc[a][r];
            s += ror16<1>(s); s += ror16<2>(s); s += ror16<4>(s); s += ror16<8>(s);
            m = fmaxf(m, ror16<1>(m)); m = fmaxf(m, ror16<2>(m));
            m = fmaxf(m, ror16<4>(m)); m = fmaxf(m, ror16<8>(m));
            if (mrow == 0)
                pslot[(size_t)cs * B_ROWS + rowb + a * 16 + quad * 4 + r] =
                    make_float2(m, s);
        }
}

// ---------------------------------------------------------------------------
// finalize2: merge 128 fp32 slots/row, ArcFace margin correction, loss+prec1.
// ---------------------------------------------------------------------------
__global__ __launch_bounds__(256)
void finalize2_kernel(const float2* __restrict__ pslot,
                      const float* __restrict__ x, const float* __restrict__ w,
                      const int* __restrict__ label,
                      float* __restrict__ accum, float* __restrict__ out)
{
    __shared__ float2 red[8][32];
    const int t = threadIdx.x, rr = t & 31, g = t >> 5;
    {
        const int row = blockIdx.x * 32 + rr;
        float M = -1e30f, L = 0.f;
        #pragma unroll
        for (int s = 0; s < NSLOT2 / 8; ++s) {
            float2 p = pslot[(size_t)(s * 8 + g) * B_ROWS + row];
            M = fmaxf(M, p.x);
            L += p.y;
        }
        red[g][rr] = make_float2(M, L);
    }
    __syncthreads();
    if (t < 32) {
        const int row = blockIdx.x * 32 + t;
        float Mc = -1e30f, L = 0.f;
        #pragma unroll
        for (int g2 = 0; g2 < 8; ++g2) {
            float2 p = red[g2][t];
            Mc = fmaxf(Mc, p.x);
            L += p.y;
        }

        const int lab = label[row];
        const float4* xr = (const float4*)(x + (size_t)row * DIM);
        const float4* wr = (const float4*)(w + (size_t)lab * DIM);
        float dot = 0.f, nx = 0.f, nw = 0.f;
        #pragma unroll
        for (int q = 0; q < 48; ++q) {
            float4 a = xr[q], b = wr[q];
            dot += a.x * b.x + a.y * b.y + a.z * b.z + a.w * b.w;
            nx  += a.x * a.x + a.y * a.y + a.z * a.z + a.w * a.w;
            nw  += b.x * b.x + b.y * b.y + b.z * b.z + b.w * b.w;
        }
        float cosl    = dot / fmaxf(sqrtf(nx) * sqrtf(nw), 1e-12f);
        float t_plain = S_SCALE * cosl;
        float sine    = sqrtf(fmaxf(0.f, fminf(1.f, 1.f - cosl * cosl)));
        float phi     = cosl * COS_M - sine * SIN_M;
        float modv    = ((cosl - TH_C) > 0.f) ? phi : (cosl - MM_C);
        float t_mod   = S_SCALE * modv;

        float Ladj = L - __expf(t_plain - 30.0f) + __expf(t_mod - 30.0f);
        Ladj = fmaxf(Ladj, 1e-37f);
        float loss = (30.0f + logf(Ladj)) - t_mod;
        float corr = (t_mod > S_SCALE * Mc) ? 1.f : 0.f;

        #pragma unroll
        for (int off = 16; off > 0; off >>= 1) {
            loss += __shfl_xor(loss, off);
            corr += __shfl_xor(corr, off);
        }
        if (t == 0) {
            atomicAdd(&accum[0], loss);
            atomicAdd(&accum[1], corr);
            __threadfence();
            int old = atomicAdd((int*)accum + 2, 1);
            if (old == (int)gridDim.x - 1) {
                float a0 = atomicAdd(&accum[0], 0.0f);
                float a1 = atomicAdd(&accum[1], 0.0f);
                out[0] = a0 * (1.0f / (float)B_ROWS);
                out[1] = a1 * (100.0f / (float)B_ROWS);
            }
        }
    }
}

// ===========================================================================
// OLD PATH (verified fallback, used only if workspace is too small)
// ===========================================================================

__global__ __launch_bounds__(256)
void prep_kernel(const float* __restrict__ x, unsigned short* __restrict__ asw,
                 float* __restrict__ accum)
{
    const int ab = blockIdx.x;            // 0..7
    const int t = threadIdx.x;
    if (ab == 0 && t < 4) accum[t] = 0.0f;
    const int r = t >> 1, half = t & 1;
    const int row = ab * 128 + r;
    const int c = ab * 2 + (r >> 6);      // A chunk index (64-row chunks)
    const int r64 = r & 63;

    float4 buf[24];
    float s = 0.f;
    const float4* sp = (const float4*)(x + (size_t)row * DIM) + half * 24;
    #pragma unroll
    for (int q = 0; q < 24; ++q) {
        float4 v = sp[q];
        buf[q] = v;
        s += v.x * v.x + v.y * v.y + v.z * v.z + v.w * v.w;
    }
    s += __shfl_xor(s, 1);
    const float inv = 1.0f / fmaxf(sqrtf(s), 1e-12f);
    #pragma unroll
    for (int j = 0; j < 12; ++j) {
        const int k8 = half * 12 + j;
        uint4 o;
        float4 a0 = buf[2 * j], a1 = buf[2 * j + 1];
        o.x = pack2(a0.x * inv, a0.y * inv);
        o.y = pack2(a0.z * inv, a0.w * inv);
        o.z = pack2(a1.x * inv, a1.y * inv);
        o.w = pack2(a1.z * inv, a1.w * inv);
        *(uint4*)(asw + ((size_t)c * ASEG_CH + k8 * 64 + r64) * 8) = o;
    }
}

__global__ __launch_bounds__(256, 3)
void gemm_stats_kernel(const float* __restrict__ w,
                       const unsigned short* __restrict__ asw,
                       unsigned int* __restrict__ pslot)
{
    __shared__ __align__(16) char lds[49152];
    const int tid  = threadIdx.x;
    const int wave = tid >> 6;
    const int lane = tid & 63;
    const int quad = lane >> 4;
    const int mrow = lane & 15;
    const int rg   = wave >> 1;
    const int cgr  = wave & 1;

    {
        const int r = tid >> 1, half = tid & 1;
        const int col = blockIdx.x * 128 + r;
        const bool live = (col < NCLS);
        float4 buf[24];
        float s = 0.f;
        if (live) {
            const float4* sp = (const float4*)(w + (size_t)col * DIM) + half * 24;
            #pragma unroll
            for (int q = 0; q < 24; ++q) {
                float4 v = sp[q];
                buf[q] = v;
                s += v.x * v.x + v.y * v.y + v.z * v.z + v.w * v.w;
            }
        }
        s += __shfl_xor(s, 1);
        const float inv = live ? (1.0f / fmaxf(sqrtf(s), 1e-12f)) : 0.0f;
        #pragma unroll
        for (int j = 0; j < 12; ++j) {
            const int k8 = half * 12 + j;
            uint4 o = make_uint4(0u, 0u, 0u, 0u);
            if (live) {
                float4 a0 = buf[2 * j], a1 = buf[2 * j + 1];
                o.x = pack2(a0.x * inv, a0.y * inv);
                o.y = pack2(a0.z * inv, a0.w * inv);
                o.z = pack2(a1.x * inv, a1.y * inv);
                o.w = pack2(a1.z * inv, a1.w * inv);
            }
            *(uint4*)(lds + (size_t)(k8 * 128 + r) * 16) = o;
        }
    }
    __syncthreads();

    bf16x8 bfr[6][4];
    #pragma unroll
    for (int ks = 0; ks < 6; ++ks)
        #pragma unroll
        for (int ni = 0; ni < 4; ++ni)
            bfr[ks][ni] = *(const bf16x8*)(lds +
                (((ks * 4 + quad) * 128) + cgr * 64 + ni * 16 + mrow) * 16);

    const int slot = blockIdx.x * 2 + cgr;
    #pragma unroll 2
    for (int c = 0; c < NCHUNKR; ++c) {
        const unsigned short* ab = asw + (size_t)c * ASEG_CH * 8;
        floatx4 acc[2][4];
        #pragma unroll
        for (int mi = 0; mi < 2; ++mi)
            #pragma unroll
            for (int ni = 0; ni < 4; ++ni) {
                floatx4 z = {0.f, 0.f, 0.f, 0.f};
                acc[mi][ni] = z;
            }
        #pragma unroll
        for (int ks = 0; ks < 6; ++ks) {
            bf16x8 a0 = *(const bf16x8*)(ab +
                (size_t)(((ks * 4 + quad) * 64) + rg * 32 + mrow) * 8);
            bf16x8 a1 = *(const bf16x8*)(ab +
                (size_t)(((ks * 4 + quad) * 64) + rg * 32 + 16 + mrow) * 8);
            #pragma unroll
            for (int ni = 0; ni < 4; ++ni)
                acc[0][ni] = __builtin_amdgcn_mfma_f32_16x16x32_bf16(
                    a0, bfr[ks][ni], acc[0][ni], 0, 0, 0);
            #pragma unroll
            for (int ni = 0; ni < 4; ++ni)
                acc[1][ni] = __builtin_amdgcn_mfma_f32_16x16x32_bf16(
                    a1, bfr[ks][ni], acc[1][ni], 0, 0, 0);
        }

        #pragma unroll
        for (int mi = 0; mi < 2; ++mi)
            #pragma unroll
            for (int r = 0; r < 4; ++r) {
                float v0 = acc[mi][0][r], v1 = acc[mi][1][r];
                float v2 = acc[mi][2][r], v3 = acc[mi][3][r];
                float m = fmaxf(fmaxf(v0, v1), fmaxf(v2, v3));
                float s = fexp2(fmaf(v0, L2E30, -L2E30))
                        + fexp2(fmaf(v1, L2E30, -L2E30))
                        + fexp2(fmaf(v2, L2E30, -L2E30))
                        + fexp2(fmaf(v3, L2E30, -L2E30));
                s += ror16<1>(s); s += ror16<2>(s);
                s += ror16<4>(s); s += ror16<8>(s);
                m = fmaxf(m, ror16<1>(m)); m = fmaxf(m, ror16<2>(m));
                m = fmaxf(m, ror16<4>(m)); m = fmaxf(m, ror16<8>(m));
                if (mrow == mi * 4 + r)
                    pslot[(size_t)slot * B_ROWS +
                          c * 64 + rg * 32 + mi * 16 + quad * 4 + r] = pack2(m, s);
            }
    }
}

__global__ __launch_bounds__(256)
void finalize_kernel(const unsigned int* __restrict__ pslot,
                     const float* __restrict__ x, const float* __restrict__ w,
                     const int* __restrict__ label,
                     float* __restrict__ accum, float* __restrict__ out)
{
    __shared__ float2 red[8][32];
    const int t = threadIdx.x, rr = t & 31, g = t >> 5;
    {
        const int row = blockIdx.x * 32 + rr;
        float M = -1e30f, L = 0.f;
        for (int s = g; s < NSLOT; s += 8) {
            unsigned int u = pslot[(size_t)s * B_ROWS + row];
            M = fmaxf(M, __uint_as_float(u << 16));
            L += __uint_as_float(u & 0xFFFF0000u);
        }
        red[g][rr] = make_float2(M, L);
    }
    __syncthreads();
    if (t < 32) {
        const int row = blockIdx.x * 32 + t;
        float Mc = -1e30f, L = 0.f;
        #pragma unroll
        for (int g2 = 0; g2 < 8; ++g2) {
            float2 p = red[g2][t];
            Mc = fmaxf(Mc, p.x);
            L += p.y;
        }

        const int lab = label[row];
        const float4* xr = (const float4*)(x + (size_t)row * DIM);
        const float4* wr = (const float4*)(w + (size_t)lab * DIM);
        float dot = 0.f, nx = 0.f, nw = 0.f;
        #pragma unroll
        for (int q = 0; q < 48; ++q) {
            float4 a = xr[q], b = wr[q];
            dot += a.x * b.x + a.y * b.y + a.z * b.z + a.w * b.w;
            nx  += a.x * a.x + a.y * a.y + a.z * a.z + a.w * a.w;
            nw  += b.x * b.x + b.y * b.y + b.z * b.z + b.w * b.w;
        }
        float cosl    = dot / fmaxf(sqrtf(nx) * sqrtf(nw), 1e-12f);
        float t_plain = S_SCALE * cosl;
        float sine    = sqrtf(fmaxf(0.f, fminf(1.f, 1.f - cosl * cosl)));
        float phi     = cosl * COS_M - sine * SIN_M;
        float modv    = ((cosl - TH_C) > 0.f) ? phi : (cosl - MM_C);
        float t_mod   = S_SCALE * modv;

        float Ladj = L - __expf(t_plain - 30.0f) + __expf(t_mod - 30.0f);
        Ladj = fmaxf(Ladj, 1e-37f);
        float loss = (30.0f + logf(Ladj)) - t_mod;
        float corr = (t_mod > S_SCALE * Mc) ? 1.f : 0.f;

        #pragma unroll
        for (int off = 16; off > 0; off >>= 1) {
            loss += __shfl_xor(loss, off);
            corr += __shfl_xor(corr, off);
        }
        if (t == 0) {
            atomicAdd(&accum[0], loss);
            atomicAdd(&accum[1], corr);
            __threadfence();
            int old = atomicAdd((int*)accum + 2, 1);
            if (old == (int)gridDim.x - 1) {
                float a0 = atomicAdd(&accum[0], 0.0f);
                float a1 = atomicAdd(&accum[1], 0.0f);
                out[0] = a0 * (1.0f / (float)B_ROWS);
                out[1] = a1 * (100.0f / (float)B_ROWS);
            }
        }
    }
}

// ---------------------------------------------------------------------------
extern "C" void kernel_launch(void* const* d_in, const int* in_sizes, int n_in,
                              void* d_out, int out_size, void* d_ws, size_t ws_size,
                              hipStream_t stream)
{
    const float* x     = (const float*)d_in[0];
    const float* w     = (const float*)d_in[1];
    const int*   label = (const int*)d_in[2];
    float* out = (float*)d_out;

    char* ws = (char*)d_ws;
    float* accum = (float*)ws;
    unsigned short* asw = (unsigned short*)(ws + 256);
    const size_t asw_bytes = (size_t)NCHUNKR * ASEG_CH * 16;           // 393216

    const size_t wsw_bytes    = (size_t)NCHUNKC * 24 * 64 * 16;       // 38535168
    const size_t pslot2_bytes = (size_t)NSLOT2 * B_ROWS * 8;          // 1048576
    const size_t need_new = 256 + asw_bytes + wsw_bytes + pslot2_bytes;

    if (ws_size >= need_new) {
        unsigned short* wsw = (unsigned short*)(ws + 256 + asw_bytes);
        float2* pslot2 = (float2*)(ws + 256 + asw_bytes + wsw_bytes);
        pack_kernel<<<dim3(PACK_GRID), dim3(256), 0, stream>>>(x, w, asw, wsw, accum);
        gemm_stats3_kernel<<<dim3(4 * CSPLIT), dim3(256), 0, stream>>>(asw, wsw, pslot2);
        finalize2_kernel<<<dim3(B_ROWS / 32), dim3(256), 0, stream>>>(
            pslot2, x, w, label, accum, out);
    } else {
        unsigned int* pslot = (unsigned int*)(ws + 256 + asw_bytes);
        prep_kernel<<<dim3(8), dim3(256), 0, stream>>>(x, asw, accum);
        gemm_stats_kernel<<<dim3(NTILE_B), dim3(256), 0, stream>>>(w, asw, pslot);
        finalize_kernel<<<dim3(B_ROWS / 32), dim3(256), 0, stream>>>(
            pslot, x, w, label, accum, out);
    }
}